// Round 1
// baseline (709.529 us; speedup 1.0000x reference)
//
#include <hip/hip_runtime.h>

typedef __bf16 bf16;
typedef __bf16 bf16x8 __attribute__((ext_vector_type(8)));
typedef float  f32x4  __attribute__((ext_vector_type(4)));

#define C_    384
#define V_    32768
#define NTOT  12582912.0f   // 384*32768 elements per batch for GroupNorm
#define EPS_  1e-5f
#define WMAT  147456        // 384*384

// ---- async global->LDS, 16B per lane ----
__device__ __forceinline__ void g2l16(const void* g, void* l) {
    __builtin_amdgcn_global_load_lds(
        (const __attribute__((address_space(1))) void*)g,
        (__attribute__((address_space(3))) void*)l, 16, 0, 0);
}

// NaN-safe tanh-approx GELU: x * 0.5*(1+tanh(t)) = x / (1 + exp(-2t))
__device__ __forceinline__ float gelu_t(float x) {
    float u = -1.5957691216f * x * (1.0f + 0.044715f * x * x);
    return x / (1.0f + __expf(u));
}

__device__ __forceinline__ float wave_sum(float v) {
#pragma unroll
    for (int off = 32; off > 0; off >>= 1) v += __shfl_down(v, off, 64);
    return v;
}

// =================== P1: weights fp32 -> bf16 (w1,w21,w22,w23) ===================
__global__ void k_wcast(const float* __restrict__ w1, const float* __restrict__ w21,
                        const float* __restrict__ w22, const float* __restrict__ w23,
                        bf16* __restrict__ wb) {
    int i = (blockIdx.x * 256 + threadIdx.x) * 4;  // 4*147456 floats total
    const float* srcs[4] = {w1, w21, w22, w23};
    int t = i / WMAT;
    int j = i - t * WMAT;
    const float4 v = *(const float4*)(srcs[t] + j);
    bf16* d = wb + i;
    d[0] = (bf16)v.x; d[1] = (bf16)v.y; d[2] = (bf16)v.z; d[3] = (bf16)v.w;
}

// =================== P2: x [b][c][v] fp32 -> xb [b][v][c] bf16 ===================
__global__ void k_txp(const float* __restrict__ x, bf16* __restrict__ xb) {
    __shared__ float tile[32][65];
    int bid = blockIdx.x;                   // 2 * 512 * 12
    int cb = bid % 12;
    int vb = (bid / 12) & 511;
    int b  = bid / (12 * 512);
    int c0 = cb * 32, v0 = vb * 64;
    int t = threadIdx.x;
    int vl = t & 63, cl = t >> 6;
    const float* src = x + ((size_t)(b * C_ + c0)) * V_ + v0;
#pragma unroll
    for (int i = 0; i < 8; i++)
        tile[cl + i * 4][vl] = src[(size_t)(cl + i * 4) * V_ + vl];
    __syncthreads();
    int vl2 = t >> 2, cl2 = (t & 3) * 8;
    bf16x8 o;
#pragma unroll
    for (int j = 0; j < 8; j++) o[j] = (bf16)tile[cl2 + j][vl2];
    *(bf16x8*)(xb + ((size_t)(b * V_ + v0 + vl2)) * C_ + c0 + cl2) = o;
}

// =================== shared MFMA GEMM core: 128x128 tile, K=384, BK=32 ===================
// A: activations [v][c] (k-contig rows), Bw: weights [o][c] (k-contig rows)
__device__ __forceinline__ void gemm_core(const bf16* __restrict__ A, const bf16* __restrict__ Bw,
                                          bf16* sA, bf16* sB, f32x4 acc[4][4]) {
    const int tid  = threadIdx.x;
    const int lane = tid & 63;
    const int wv   = tid >> 6;
    const int wm   = (wv & 1) * 64, wn = (wv >> 1) * 64;
    const int lrow = lane & 15;
    const int lkB  = (lane >> 4) * 16;   // byte offset within 64B row
    const bf16* ga = A  + (tid >> 2) * C_ + (tid & 3) * 8;
    const bf16* gb = Bw + (tid >> 2) * C_ + (tid & 3) * 8;
    char* la = (char*)sA + tid * 16;
    char* lb = (char*)sB + tid * 16;
    const char* ra = (const char*)sA;
    const char* rb = (const char*)sB;
    for (int k0 = 0; k0 < C_; k0 += 32) {
        __syncthreads();
        g2l16(ga + k0,           la);
        g2l16(ga + k0 + 64 * C_, la + 4096);
        g2l16(gb + k0,           lb);
        g2l16(gb + k0 + 64 * C_, lb + 4096);
        __syncthreads();
        bf16x8 af[4], bfr[4];
#pragma unroll
        for (int i = 0; i < 4; i++)
            af[i] = *(const bf16x8*)(ra + (wm + i * 16 + lrow) * 64 + lkB);
#pragma unroll
        for (int i = 0; i < 4; i++)
            bfr[i] = *(const bf16x8*)(rb + (wn + i * 16 + lrow) * 64 + lkB);
#pragma unroll
        for (int mi = 0; mi < 4; mi++)
#pragma unroll
            for (int ni = 0; ni < 4; ni++)
                acc[mi][ni] = __builtin_amdgcn_mfma_f32_16x16x32_bf16(
                    af[mi], bfr[ni], acc[mi][ni], 0, 0, 0);
    }
}

__device__ __forceinline__ void tile_coords(int bid, int& b, int& m0, int& n0) {
    b = bid / 768;
    int r = bid % 768;
    m0 = (r / 3) * 128;
    n0 = (r % 3) * 128;
}

// =================== P3: GEMM1 = x @ w1 + b1 -> h1 bf16, + GN1 stats ===================
__global__ __launch_bounds__(256, 2) void k_gemm1(const bf16* __restrict__ xb, const bf16* __restrict__ w1b,
                                                  const float* __restrict__ b1, bf16* __restrict__ h1,
                                                  float* __restrict__ stats) {
    __shared__ bf16 sA[128 * 32], sB[128 * 32];
    int b, m0, n0; tile_coords(blockIdx.x, b, m0, n0);
    f32x4 acc[4][4];
#pragma unroll
    for (int i = 0; i < 4; i++)
#pragma unroll
        for (int j = 0; j < 4; j++)
#pragma unroll
            for (int r = 0; r < 4; r++) acc[i][j][r] = 0.f;
    gemm_core(xb + ((size_t)(b * V_) + m0) * C_, w1b + n0 * C_, sA, sB, acc);
    int lane = threadIdx.x & 63, wv = threadIdx.x >> 6;
    int wm = (wv & 1) * 64, wn = (wv >> 1) * 64;
    int col = lane & 15, rowq = (lane >> 4) * 4;
    float s = 0.f, ss = 0.f;
#pragma unroll
    for (int ni = 0; ni < 4; ni++) {
        int o = n0 + wn + ni * 16 + col;
        float bias = b1[o];
#pragma unroll
        for (int mi = 0; mi < 4; mi++) {
            size_t vb = (size_t)(b * V_) + m0 + wm + mi * 16 + rowq;
#pragma unroll
            for (int rg = 0; rg < 4; rg++) {
                float val = acc[mi][ni][rg] + bias;
                s += val; ss += val * val;
                h1[(vb + rg) * C_ + o] = (bf16)val;
            }
        }
    }
    s = wave_sum(s); ss = wave_sum(ss);
    if (lane == 0) { atomicAdd(&stats[2 * b], s); atomicAdd(&stats[2 * b + 1], ss); }
}

// =================== P4: GN1 + GELU + 3 axial shifts ===================
__device__ __forceinline__ void axis_out(const bf16* __restrict__ h1, size_t srcoff, bool ok,
                                         const float* a, const float* be,
                                         bf16* __restrict__ dst, size_t obase) {
    bf16x8 outv;
    if (ok) {
        bf16x8 xin = *(const bf16x8*)(h1 + srcoff);
#pragma unroll
        for (int e = 0; e < 8; e++) outv[e] = (bf16)gelu_t((float)xin[e] * a[e] + be[e]);
    } else {
#pragma unroll
        for (int e = 0; e < 8; e++) outv[e] = (bf16)0.f;
    }
    *(bf16x8*)(dst + obase) = outv;
}

__global__ void k_shift(const bf16* __restrict__ h1, const float* __restrict__ g1,
                        const float* __restrict__ bt1, const float* __restrict__ stats,
                        bf16* __restrict__ std_, bf16* __restrict__ slr, bf16* __restrict__ shd) {
    int idx = blockIdx.x * 256 + threadIdx.x;   // 2*32768*48 threads
    int cg = idx % 48;
    int t2 = idx / 48;
    int v = t2 & (V_ - 1);
    int b = t2 >> 15;
    float inv  = 1.0f / NTOT;
    float mean = stats[2 * b] * inv;
    float var  = stats[2 * b + 1] * inv - mean * mean;
    float rstd = rsqrtf(var + EPS_);
    int chunk = cg >> 4;
    int dlt = 1 - chunk;                        // +1 / 0 / -1 per 128-ch chunk
    int d = v >> 10, hh = (v >> 5) & 31, w = v & 31;
    int c0 = cg * 8;
    float a[8], be[8];
    {
        const float4 gA = *(const float4*)(g1 + c0);
        const float4 gB = *(const float4*)(g1 + c0 + 4);
        const float4 bA = *(const float4*)(bt1 + c0);
        const float4 bB = *(const float4*)(bt1 + c0 + 4);
        float gg[8] = {gA.x, gA.y, gA.z, gA.w, gB.x, gB.y, gB.z, gB.w};
        float bb[8] = {bA.x, bA.y, bA.z, bA.w, bB.x, bB.y, bB.z, bB.w};
#pragma unroll
        for (int e = 0; e < 8; e++) { a[e] = rstd * gg[e]; be[e] = bb[e] - mean * a[e]; }
    }
    size_t rowb  = (size_t)b * V_;
    size_t obase = (rowb + v) * C_ + c0;
    // D axis (td), H axis (lr), W axis (hd)
    axis_out(h1, (rowb + v + dlt * 1024) * C_ + c0, (unsigned)(d  + dlt) < 32u, a, be, std_, obase);
    axis_out(h1, (rowb + v + dlt * 32)   * C_ + c0, (unsigned)(hh + dlt) < 32u, a, be, slr,  obase);
    axis_out(h1, (rowb + v + dlt)        * C_ + c0, (unsigned)(w  + dlt) < 32u, a, be, shd,  obase);
}

// =================== P5: fused GEMM2 (3 branches) + GN2 stats ===================
__global__ __launch_bounds__(256, 2) void k_gemm2(const bf16* __restrict__ slr, const bf16* __restrict__ std_,
                                                  const bf16* __restrict__ shd, const bf16* __restrict__ wb,
                                                  const float* __restrict__ b21, const float* __restrict__ b22,
                                                  const float* __restrict__ b23, bf16* __restrict__ y,
                                                  float* __restrict__ stats) {
    __shared__ bf16 sA[128 * 32], sB[128 * 32];
    int b, m0, n0; tile_coords(blockIdx.x, b, m0, n0);
    int lane = threadIdx.x & 63, wv = threadIdx.x >> 6;
    int wm = (wv & 1) * 64, wn = (wv >> 1) * 64;
    int col = lane & 15, rowq = (lane >> 4) * 4;
    f32x4 yac[4][4];
#pragma unroll
    for (int i = 0; i < 4; i++)
#pragma unroll
        for (int j = 0; j < 4; j++)
#pragma unroll
            for (int r = 0; r < 4; r++) yac[i][j][r] = 0.f;
    const bf16*  As[3] = {slr, std_, shd};
    const bf16*  Ws[3] = {wb + WMAT, wb + 2 * WMAT, wb + 3 * WMAT};  // w21b, w22b, w23b
    const float* Bs[3] = {b21, b22, b23};
#pragma unroll
    for (int ax = 0; ax < 3; ax++) {
        f32x4 acc[4][4];
#pragma unroll
        for (int i = 0; i < 4; i++)
#pragma unroll
            for (int j = 0; j < 4; j++)
#pragma unroll
                for (int r = 0; r < 4; r++) acc[i][j][r] = 0.f;
        gemm_core(As[ax] + ((size_t)(b * V_) + m0) * C_, Ws[ax] + n0 * C_, sA, sB, acc);
#pragma unroll
        for (int ni = 0; ni < 4; ni++) {
            float bias = Bs[ax][n0 + wn + ni * 16 + col];
#pragma unroll
            for (int mi = 0; mi < 4; mi++)
#pragma unroll
                for (int rg = 0; rg < 4; rg++)
                    yac[mi][ni][rg] += gelu_t(acc[mi][ni][rg] + bias);
        }
    }
    float s = 0.f, ss = 0.f;
#pragma unroll
    for (int ni = 0; ni < 4; ni++) {
        int o = n0 + wn + ni * 16 + col;
#pragma unroll
        for (int mi = 0; mi < 4; mi++) {
            size_t vb = (size_t)(b * V_) + m0 + wm + mi * 16 + rowq;
#pragma unroll
            for (int rg = 0; rg < 4; rg++) {
                float val = yac[mi][ni][rg];
                s += val; ss += val * val;
                y[(vb + rg) * C_ + o] = (bf16)val;
            }
        }
    }
    s = wave_sum(s); ss = wave_sum(ss);
    if (lane == 0) { atomicAdd(&stats[4 + 2 * b], s); atomicAdd(&stats[5 + 2 * b], ss); }
}

// =================== P6: fold GN2 affine into W3/b3 (per batch) ===================
__global__ void k_fold(const float* __restrict__ w3, const float* __restrict__ b3,
                       const float* __restrict__ g2, const float* __restrict__ bt2,
                       const float* __restrict__ stats, bf16* __restrict__ w3p,
                       float* __restrict__ b3p) {
    int bo = blockIdx.x;           // 768 = 2*384
    int b = bo / 384, o = bo % 384;
    int l = threadIdx.x;           // 64 threads
    float inv  = 1.0f / NTOT;
    float mean = stats[4 + 2 * b] * inv;
    float var  = stats[5 + 2 * b] * inv - mean * mean;
    float rstd = rsqrtf(var + EPS_);
    float part = 0.f;
    for (int c = l; c < C_; c += 64) {
        float wv_ = w3[o * C_ + c];
        float gr  = g2[c] * rstd;
        w3p[(size_t)b * WMAT + o * C_ + c] = (bf16)(wv_ * gr);
        part += wv_ * (bt2[c] - mean * gr);
    }
    part = wave_sum(part);
    if (l == 0) b3p[bo] = b3[o] + part;
}

// =================== P7: GEMM3 -> d_out fp32, channel-first layout ===================
__global__ __launch_bounds__(256, 2) void k_gemm3(const bf16* __restrict__ y, const bf16* __restrict__ w3p,
                                                  const float* __restrict__ b3p, float* __restrict__ out) {
    __shared__ bf16 sA[128 * 32], sB[128 * 32];
    int b, m0, n0; tile_coords(blockIdx.x, b, m0, n0);
    f32x4 acc[4][4];
#pragma unroll
    for (int i = 0; i < 4; i++)
#pragma unroll
        for (int j = 0; j < 4; j++)
#pragma unroll
            for (int r = 0; r < 4; r++) acc[i][j][r] = 0.f;
    gemm_core(y + ((size_t)(b * V_) + m0) * C_, w3p + (size_t)b * WMAT + n0 * C_, sA, sB, acc);
    int lane = threadIdx.x & 63, wv = threadIdx.x >> 6;
    int wm = (wv & 1) * 64, wn = (wv >> 1) * 64;
    int col = lane & 15, rowq = (lane >> 4) * 4;
#pragma unroll
    for (int ni = 0; ni < 4; ni++) {
        int o = n0 + wn + ni * 16 + col;
        float bias = b3p[b * C_ + o];
#pragma unroll
        for (int mi = 0; mi < 4; mi++) {
            f32x4 r = acc[mi][ni];
            r[0] += bias; r[1] += bias; r[2] += bias; r[3] += bias;
            size_t adr = (size_t)b * ((size_t)C_ * V_) + (size_t)o * V_ + (m0 + wm + mi * 16 + rowq);
            *(f32x4*)(out + adr) = r;
        }
    }
}

extern "C" void kernel_launch(void* const* d_in, const int* in_sizes, int n_in,
                              void* d_out, int out_size, void* d_ws, size_t ws_size,
                              hipStream_t stream) {
    const float* x   = (const float*)d_in[0];
    const float* w1  = (const float*)d_in[1];
    const float* b1  = (const float*)d_in[2];
    const float* g1  = (const float*)d_in[3];
    const float* bt1 = (const float*)d_in[4];
    const float* w21 = (const float*)d_in[5];
    const float* b21 = (const float*)d_in[6];
    const float* w22 = (const float*)d_in[7];
    const float* b22 = (const float*)d_in[8];
    const float* w23 = (const float*)d_in[9];
    const float* b23 = (const float*)d_in[10];
    const float* g2  = (const float*)d_in[11];
    const float* bt2 = (const float*)d_in[12];
    const float* w3  = (const float*)d_in[13];
    const float* b3  = (const float*)d_in[14];
    float* out = (float*)d_out;

    char* ws = (char*)d_ws;
    const size_t HALF = 50331648ull;           // 2*384*32768*2 B / 2  (one bf16 tensor)
    bf16*  ws0   = (bf16*)ws;                  // xb (P2-P3), then sh_hd (P4-P5)
    bf16*  ws1   = (bf16*)(ws + HALF);         // h1 (P3-P4), then y (P5-P7)
    bf16*  wb    = (bf16*)(ws + 2 * HALF);                       // 1,179,648 B
    bf16*  w3p   = (bf16*)(ws + 2 * HALF + 1179648);             //   589,824 B
    float* b3p   = (float*)(ws + 2 * HALF + 1179648 + 589824);   //     3,072 B
    float* stats = (float*)(ws + 2 * HALF + 1179648 + 589824 + 3072);
    bf16* sh_td = (bf16*)d_out;                        // d_out first half as scratch
    bf16* sh_lr = (bf16*)((char*)d_out + HALF);        // d_out second half as scratch

    hipMemsetAsync(stats, 0, 64, stream);
    k_wcast<<<576,   256, 0, stream>>>(w1, w21, w22, w23, wb);
    k_txp  <<<12288, 256, 0, stream>>>(x, ws0);
    k_gemm1<<<1536,  256, 0, stream>>>(ws0, wb, b1, ws1, stats);
    k_shift<<<12288, 256, 0, stream>>>(ws1, g1, bt1, stats, sh_td, sh_lr, ws0);
    k_gemm2<<<1536,  256, 0, stream>>>(sh_lr, sh_td, ws0, wb, b21, b22, b23, ws1, stats);
    k_fold <<<768,    64, 0, stream>>>(w3, b3, g2, bt2, stats, w3p, b3p);
    k_gemm3<<<1536,  256, 0, stream>>>(ws1, w3p, b3p, out);
}